// Round 16
// baseline (119.095 us; speedup 1.0000x reference)
//
#include <hip/hip_runtime.h>

// SIREN forward, MFMA, round 16: 16 waves/CU via 512-thread blocks,
// r15's proven f32-stage epilogue unchanged.
//
// Ladder: 1526 -> 473 -> 326 -> 122.5 (r7: sc0 sc1 nt bypass stores kill the
// L2 store-miss read-fill) -> 117.5 us (r15: 12 waves/CU via 32-col f32
// stage; 128 B store pieces free). r8 weights->VGPR neutral. r10 64 B
// pieces -15%. r12 device==system scope. Bricked rounds r11/r13/r14 all
// shared the f16 stage + half4 LDS ops (suspected codegen issue); r9 was
// launch_bounds VGPR-cap. f32 stage everywhere from now on.
//
// This round: one 40 KB weight copy shared by 8 waves -> LDS 58.3 KB ->
// 2 blocks/CU x 8 waves = 16 waves/CU at VGPR=128 (4/SIMD exactly).
// Single variable vs r15: block shape 256 -> 512 (f32 stage retained).

typedef _Float16 half8 __attribute__((ext_vector_type(8)));
typedef float f32x4 __attribute__((ext_vector_type(4)));

#define OMEGA 5.0f

__global__ __launch_bounds__(512, 2) void siren_mfma_kernel(
    const float* __restrict__ coords,
    const float* __restrict__ W0, const float* __restrict__ b0,
    const float* __restrict__ W1, const float* __restrict__ b1,
    const float* __restrict__ W2, const float* __restrict__ b2,
    const float* __restrict__ W3, const float* __restrict__ b3,
    const float* __restrict__ W4, const float* __restrict__ b4,
    float* __restrict__ out, int n)
{
    // Pre-gathered A-fragment tables: [kblock][mtile][lane] -> 8 f16 (16 B).
    __shared__ half8 AT[3][2][4][64];    // hidden layers W1..W3: 24 KB
    __shared__ half8 AT4[2][8][64];      // W4: 16 KB
    __shared__ float4 w0tab[64];         // {5*W0[n][0], 5*W0[n][1], 5*b0[n], 0}
    __shared__ __align__(16) float btab[3][64];   // 5*b1..b3
    __shared__ __align__(16) float b4tab[128];    // 5*b4
    // Per-wave output slab: 16 points x 32 cols f32 (2 KB/wave, 16 KB).
    // float4-chunk XOR swizzle (3-bit), proven 0-conflict family (r5/r15).
    __shared__ float stage[8][16][32];

    const int tid  = threadIdx.x;
    const int lane = tid & 63;
    const int g    = lane >> 4;        // lane group 0..3
    const int w    = tid >> 6;         // wave in block, 0..7

    // ---------------- prep: build fragment tables (8 waves) ----------------
    {
        const float* Wp[3] = {W1, W2, W3};
        // AT: 3 layers x 8 chunks; wave w builds chunk w of each layer.
        #pragma unroll
        for (int L = 0; L < 3; ++L) {
            int b  = w >> 2, mt = w & 3;
            const float* src = Wp[L] + (16 * mt + (lane & 15)) * 64 + 32 * b + 4 * g;
            float4 wa = *(const float4*)(src);
            float4 wb = *(const float4*)(src + 16);
            half8 h;
            h[0] = (_Float16)(OMEGA * wa.x); h[1] = (_Float16)(OMEGA * wa.y);
            h[2] = (_Float16)(OMEGA * wa.z); h[3] = (_Float16)(OMEGA * wa.w);
            h[4] = (_Float16)(OMEGA * wb.x); h[5] = (_Float16)(OMEGA * wb.y);
            h[6] = (_Float16)(OMEGA * wb.z); h[7] = (_Float16)(OMEGA * wb.w);
            AT[L][b][mt][lane] = h;
        }
        // AT4: 16 chunks; wave w builds chunks w and w+8.
        #pragma unroll
        for (int c = 0; c < 2; ++c) {
            int chunk = w + 8 * c;                   // 0..15 = b*8 + mt
            int b  = chunk >> 3, mt = chunk & 7;
            const float* src = W4 + (16 * mt + (lane & 15)) * 64 + 32 * b + 4 * g;
            float4 wa = *(const float4*)(src);
            float4 wb = *(const float4*)(src + 16);
            half8 h;
            h[0] = (_Float16)(OMEGA * wa.x); h[1] = (_Float16)(OMEGA * wa.y);
            h[2] = (_Float16)(OMEGA * wa.z); h[3] = (_Float16)(OMEGA * wa.w);
            h[4] = (_Float16)(OMEGA * wb.x); h[5] = (_Float16)(OMEGA * wb.y);
            h[6] = (_Float16)(OMEGA * wb.z); h[7] = (_Float16)(OMEGA * wb.w);
            AT4[b][mt][lane] = h;
        }
        if (tid < 64) {
            w0tab[tid] = make_float4(OMEGA * W0[2 * tid], OMEGA * W0[2 * tid + 1],
                                     OMEGA * b0[tid], 0.f);
            btab[0][tid] = OMEGA * b1[tid];
            btab[1][tid] = OMEGA * b2[tid];
            btab[2][tid] = OMEGA * b3[tid];
        }
        if (tid < 128) b4tab[tid] = OMEGA * b4[tid];
    }
    __syncthreads();

    // ---------------- main loop: one wave = 16 points per batch ----------------
    const int p   = lane & 15;                // point-in-batch (= MFMA column)
    const int sr8 = lane >> 3;                // store-side row-in-octet (0..7)
    const int q3  = lane & 7;                 // store-side float4 chunk 0..7
    const int nb  = (n + 15) >> 4;
    const int wv  = blockIdx.x * 8 + w;
    const int nw  = gridDim.x * 8;

    for (int batch = wv; batch < nb; batch += nw) {
        int point = batch * 16 + p;
        int pt    = point < n ? point : n - 1;
        float2 c2 = *(const float2*)(coords + 2ull * (unsigned)pt);

        // Layer 0 (fp32 VALU): lane computes Z0[nrn][p] for nrn = 16t+4g+r,
        // landing directly in B-fragment slots: zb[t>>1][4*(t&1)+r].
        half8 zb[2];
        #pragma unroll
        for (int t = 0; t < 4; ++t) {
            #pragma unroll
            for (int r = 0; r < 4; ++r) {
                float4 ww = w0tab[16 * t + 4 * g + r];
                float z = __sinf(fmaf(c2.x, ww.x, fmaf(c2.y, ww.y, ww.z)));
                zb[t >> 1][4 * (t & 1) + r] = (_Float16)z;
            }
        }

        // Hidden layers 1..3
        #pragma unroll
        for (int L = 0; L < 3; ++L) {
            f32x4 acc[4];
            #pragma unroll
            for (int t = 0; t < 4; ++t) {
                float4 bv = *(const float4*)&btab[L][16 * t + 4 * g];
                acc[t][0] = bv.x; acc[t][1] = bv.y; acc[t][2] = bv.z; acc[t][3] = bv.w;
            }
            #pragma unroll
            for (int b = 0; b < 2; ++b) {
                #pragma unroll
                for (int mt = 0; mt < 4; ++mt) {
                    acc[mt] = __builtin_amdgcn_mfma_f32_16x16x32_f16(
                        AT[L][b][mt][lane], zb[b], acc[mt], 0, 0, 0);
                }
            }
            // activation + repack: D-regs -> next B-frags, all in-lane
            half8 zn[2];
            #pragma unroll
            for (int t = 0; t < 4; ++t) {
                #pragma unroll
                for (int r = 0; r < 4; ++r) {
                    zn[t >> 1][4 * (t & 1) + r] = (_Float16)__sinf(acc[t][r]);
                }
            }
            zb[0] = zn[0]; zb[1] = zn[1];
        }

        // Output layer: 64 -> 128 in FOUR 32-col passes (r15-identical).
        // Each pass: 2 mt-tiles MFMA+sin -> f32 slab (3-bit chunk XOR
        // swizzle) -> 2 store instructions (rows {8i..8i+7} x 128 B pieces),
        // sc0 sc1 nt bypass (no L2 read-for-ownership, r7).
        #pragma unroll
        for (int P = 0; P < 4; ++P) {
            #pragma unroll
            for (int m = 0; m < 2; ++m) {
                int mt = 2 * P + m;
                float4 bv = *(const float4*)&b4tab[16 * mt + 4 * g];
                f32x4 a4;
                a4[0] = bv.x; a4[1] = bv.y; a4[2] = bv.z; a4[3] = bv.w;
                a4 = __builtin_amdgcn_mfma_f32_16x16x32_f16(AT4[0][mt][lane], zb[0], a4, 0, 0, 0);
                a4 = __builtin_amdgcn_mfma_f32_16x16x32_f16(AT4[1][mt][lane], zb[1], a4, 0, 0, 0);
                f32x4 o;
                o[0] = __sinf(a4[0]); o[1] = __sinf(a4[1]);
                o[2] = __sinf(a4[2]); o[3] = __sinf(a4[3]);
                int qc = (4 * m + g) ^ (p & 7);      // 3-bit chunk swizzle
                *(f32x4*)&stage[w][p][4 * qc] = o;
            }
            #pragma unroll
            for (int i = 0; i < 2; ++i) {
                int row = 8 * i + sr8;
                int sq  = q3 ^ (row & 7);            // matching 3-bit swizzle
                f32x4 o4 = *(const f32x4*)&stage[w][row][4 * sq];
                int pointp = batch * 16 + row;
                if (pointp < n) {
                    float* gp = out + (size_t)pointp * 128 + 32 * P + 4 * q3;
                    asm volatile("global_store_dwordx4 %0, %1, off sc0 sc1 nt"
                                 :: "v"(gp), "v"(o4) : "memory");
                }
            }
        }
    }
}

extern "C" void kernel_launch(void* const* d_in, const int* in_sizes, int n_in,
                              void* d_out, int out_size, void* d_ws, size_t ws_size,
                              hipStream_t stream) {
    const float* coords = (const float*)d_in[0];
    const float* W0 = (const float*)d_in[1];
    const float* b0 = (const float*)d_in[2];
    const float* W1 = (const float*)d_in[3];
    const float* b1 = (const float*)d_in[4];
    const float* W2 = (const float*)d_in[5];
    const float* b2 = (const float*)d_in[6];
    const float* W3 = (const float*)d_in[7];
    const float* b3 = (const float*)d_in[8];
    const float* W4 = (const float*)d_in[9];
    const float* b4 = (const float*)d_in[10];
    float* out = (float*)d_out;

    int n = in_sizes[0] / 2;  // coords is (N, 2)
    int nb = (n + 15) / 16;
    int blocks = 512;         // 2 blocks/CU (58.3 KB LDS), 8 waves each
    int maxb = (nb + 7) / 8;
    if (blocks > maxb) blocks = maxb;
    hipLaunchKernelGGL(siren_mfma_kernel, dim3(blocks), dim3(512), 0, stream,
                       coords, W0, b0, W1, b1, W2, b2, W3, b3, W4, b4, out, n);
}

// Round 17
// 117.494 us; speedup vs baseline: 1.0136x; 1.0136x over previous
//
#include <hip/hip_runtime.h>

// SIREN forward, MFMA, round 17: r15 champion + epilogue issue-overhead trim.
//
// Ladder: 1526 -> 473 -> 326 -> 122.5 (r7: sc0 sc1 nt bypass stores kill the
// L2 store-miss read-fill) -> 117.5 us (r15: 12 waves/CU, 32-col f32 stage,
// 128 B store pieces free). Occupancy curve mapped: 8w=122.5, 12w=117.5,
// 16w=119.1 (r16) -> drain path saturates ~5.3 TB/s at >=12 waves/CU.
// r8 weights->VGPR neutral; r10 64 B pieces -15%; r12 device==system scope;
// r11/r13/r14 bricks shared the f16-stage/half4-LDS pattern (avoided).
//
// This round (last lever before roofline): per-batch WAVE-UNIFORM store
// guard (batch is uniform; N%16==0 -> all batches full; s_branch instead of
// 8x exec-mask setup) and DROP the "memory" clobber on the store asm (o4 is
// a register input; LDS WAR ordering is tracked by alias analysis) so the
// compiler can overlap next-pass/next-batch work with store issue.

typedef _Float16 half8 __attribute__((ext_vector_type(8)));
typedef float f32x4 __attribute__((ext_vector_type(4)));

#define OMEGA 5.0f

__global__ __launch_bounds__(256, 2) void siren_mfma_kernel(
    const float* __restrict__ coords,
    const float* __restrict__ W0, const float* __restrict__ b0,
    const float* __restrict__ W1, const float* __restrict__ b1,
    const float* __restrict__ W2, const float* __restrict__ b2,
    const float* __restrict__ W3, const float* __restrict__ b3,
    const float* __restrict__ W4, const float* __restrict__ b4,
    float* __restrict__ out, int n)
{
    // Pre-gathered A-fragment tables: [kblock][mtile][lane] -> 8 f16 (16 B).
    __shared__ half8 AT[3][2][4][64];    // hidden layers W1..W3: 24 KB
    __shared__ half8 AT4[2][8][64];      // W4: 16 KB
    __shared__ float4 w0tab[64];         // {5*W0[n][0], 5*W0[n][1], 5*b0[n], 0}
    __shared__ __align__(16) float btab[3][64];   // 5*b1..b3
    __shared__ __align__(16) float b4tab[128];    // 5*b4
    // Per-wave output slab: 16 points x 32 cols f32 (2 KB/wave, 8 KB).
    // float4-chunk XOR swizzle (3-bit), proven 0-conflict family (r5/r15).
    __shared__ float stage[4][16][32];

    const int tid  = threadIdx.x;
    const int lane = tid & 63;
    const int g    = lane >> 4;        // lane group 0..3
    const int w    = tid >> 6;         // wave in block

    // ---------------- prep: build fragment tables (r7-identical) ----------------
    {
        const float* Wp[3] = {W1, W2, W3};
        #pragma unroll
        for (int L = 0; L < 3; ++L) {
            #pragma unroll
            for (int c = 0; c < 2; ++c) {
                int chunk = w + 4 * c;               // 0..7 = b*4 + mt
                int b  = chunk >> 2, mt = chunk & 3;
                const float* src = Wp[L] + (16 * mt + (lane & 15)) * 64 + 32 * b + 4 * g;
                float4 wa = *(const float4*)(src);
                float4 wb = *(const float4*)(src + 16);
                half8 h;
                h[0] = (_Float16)(OMEGA * wa.x); h[1] = (_Float16)(OMEGA * wa.y);
                h[2] = (_Float16)(OMEGA * wa.z); h[3] = (_Float16)(OMEGA * wa.w);
                h[4] = (_Float16)(OMEGA * wb.x); h[5] = (_Float16)(OMEGA * wb.y);
                h[6] = (_Float16)(OMEGA * wb.z); h[7] = (_Float16)(OMEGA * wb.w);
                AT[L][b][mt][lane] = h;
            }
        }
        #pragma unroll
        for (int c = 0; c < 4; ++c) {
            int chunk = w + 4 * c;                   // 0..15 = b*8 + mt
            int b  = chunk >> 3, mt = chunk & 7;
            const float* src = W4 + (16 * mt + (lane & 15)) * 64 + 32 * b + 4 * g;
            float4 wa = *(const float4*)(src);
            float4 wb = *(const float4*)(src + 16);
            half8 h;
            h[0] = (_Float16)(OMEGA * wa.x); h[1] = (_Float16)(OMEGA * wa.y);
            h[2] = (_Float16)(OMEGA * wa.z); h[3] = (_Float16)(OMEGA * wa.w);
            h[4] = (_Float16)(OMEGA * wb.x); h[5] = (_Float16)(OMEGA * wb.y);
            h[6] = (_Float16)(OMEGA * wb.z); h[7] = (_Float16)(OMEGA * wb.w);
            AT4[b][mt][lane] = h;
        }
        if (tid < 64) {
            w0tab[tid] = make_float4(OMEGA * W0[2 * tid], OMEGA * W0[2 * tid + 1],
                                     OMEGA * b0[tid], 0.f);
            btab[0][tid] = OMEGA * b1[tid];
            btab[1][tid] = OMEGA * b2[tid];
            btab[2][tid] = OMEGA * b3[tid];
        }
        if (tid < 128) b4tab[tid] = OMEGA * b4[tid];
    }
    __syncthreads();

    // ---------------- main loop: one wave = 16 points per batch ----------------
    const int p   = lane & 15;                // point-in-batch (= MFMA column)
    const int sr8 = lane >> 3;                // store-side row-in-octet (0..7)
    const int q3  = lane & 7;                 // store-side float4 chunk 0..7
    const int nb  = (n + 15) >> 4;
    const int wv  = blockIdx.x * 4 + w;
    const int nw  = gridDim.x * 4;

    for (int batch = wv; batch < nb; batch += nw) {
        int point = batch * 16 + p;
        int pt    = point < n ? point : n - 1;
        float2 c2 = *(const float2*)(coords + 2ull * (unsigned)pt);
        const bool full = (batch * 16 + 16) <= n;   // wave-uniform

        // Layer 0 (fp32 VALU): lane computes Z0[nrn][p] for nrn = 16t+4g+r,
        // landing directly in B-fragment slots: zb[t>>1][4*(t&1)+r].
        half8 zb[2];
        #pragma unroll
        for (int t = 0; t < 4; ++t) {
            #pragma unroll
            for (int r = 0; r < 4; ++r) {
                float4 ww = w0tab[16 * t + 4 * g + r];
                float z = __sinf(fmaf(c2.x, ww.x, fmaf(c2.y, ww.y, ww.z)));
                zb[t >> 1][4 * (t & 1) + r] = (_Float16)z;
            }
        }

        // Hidden layers 1..3
        #pragma unroll
        for (int L = 0; L < 3; ++L) {
            f32x4 acc[4];
            #pragma unroll
            for (int t = 0; t < 4; ++t) {
                float4 bv = *(const float4*)&btab[L][16 * t + 4 * g];
                acc[t][0] = bv.x; acc[t][1] = bv.y; acc[t][2] = bv.z; acc[t][3] = bv.w;
            }
            #pragma unroll
            for (int b = 0; b < 2; ++b) {
                #pragma unroll
                for (int mt = 0; mt < 4; ++mt) {
                    acc[mt] = __builtin_amdgcn_mfma_f32_16x16x32_f16(
                        AT[L][b][mt][lane], zb[b], acc[mt], 0, 0, 0);
                }
            }
            // activation + repack: D-regs -> next B-frags, all in-lane
            half8 zn[2];
            #pragma unroll
            for (int t = 0; t < 4; ++t) {
                #pragma unroll
                for (int r = 0; r < 4; ++r) {
                    zn[t >> 1][4 * (t & 1) + r] = (_Float16)__sinf(acc[t][r]);
                }
            }
            zb[0] = zn[0]; zb[1] = zn[1];
        }

        // Output layer: 64 -> 128 in FOUR 32-col passes (r15-identical
        // structure). Each pass: 2 mt-tiles MFMA+sin -> f32 slab (3-bit
        // chunk XOR swizzle) -> 2 store instructions (rows {8i..8i+7} x
        // 128 B pieces), sc0 sc1 nt bypass (no L2 RFO, r7). Store asm has
        // NO memory clobber (register-only input; LDS order via alias
        // analysis) and the bounds guard is a single wave-uniform branch.
        #pragma unroll
        for (int P = 0; P < 4; ++P) {
            #pragma unroll
            for (int m = 0; m < 2; ++m) {
                int mt = 2 * P + m;
                float4 bv = *(const float4*)&b4tab[16 * mt + 4 * g];
                f32x4 a4;
                a4[0] = bv.x; a4[1] = bv.y; a4[2] = bv.z; a4[3] = bv.w;
                a4 = __builtin_amdgcn_mfma_f32_16x16x32_f16(AT4[0][mt][lane], zb[0], a4, 0, 0, 0);
                a4 = __builtin_amdgcn_mfma_f32_16x16x32_f16(AT4[1][mt][lane], zb[1], a4, 0, 0, 0);
                f32x4 o;
                o[0] = __sinf(a4[0]); o[1] = __sinf(a4[1]);
                o[2] = __sinf(a4[2]); o[3] = __sinf(a4[3]);
                int qc = (4 * m + g) ^ (p & 7);      // 3-bit chunk swizzle
                *(f32x4*)&stage[w][p][4 * qc] = o;
            }
            if (full) {
                #pragma unroll
                for (int i = 0; i < 2; ++i) {
                    int row = 8 * i + sr8;
                    int sq  = q3 ^ (row & 7);        // matching 3-bit swizzle
                    f32x4 o4 = *(const f32x4*)&stage[w][row][4 * sq];
                    float* gp = out + (size_t)(batch * 16 + row) * 128 + 32 * P + 4 * q3;
                    asm volatile("global_store_dwordx4 %0, %1, off sc0 sc1 nt"
                                 :: "v"(gp), "v"(o4));
                }
            } else {
                #pragma unroll
                for (int i = 0; i < 2; ++i) {
                    int row = 8 * i + sr8;
                    int sq  = q3 ^ (row & 7);
                    f32x4 o4 = *(const f32x4*)&stage[w][row][4 * sq];
                    int pointp = batch * 16 + row;
                    if (pointp < n) {
                        float* gp = out + (size_t)pointp * 128 + 32 * P + 4 * q3;
                        asm volatile("global_store_dwordx4 %0, %1, off sc0 sc1 nt"
                                     :: "v"(gp), "v"(o4));
                    }
                }
            }
        }
    }
}

extern "C" void kernel_launch(void* const* d_in, const int* in_sizes, int n_in,
                              void* d_out, int out_size, void* d_ws, size_t ws_size,
                              hipStream_t stream) {
    const float* coords = (const float*)d_in[0];
    const float* W0 = (const float*)d_in[1];
    const float* b0 = (const float*)d_in[2];
    const float* W1 = (const float*)d_in[3];
    const float* b1 = (const float*)d_in[4];
    const float* W2 = (const float*)d_in[5];
    const float* b2 = (const float*)d_in[6];
    const float* W3 = (const float*)d_in[7];
    const float* b3 = (const float*)d_in[8];
    const float* W4 = (const float*)d_in[9];
    const float* b4 = (const float*)d_in[10];
    float* out = (float*)d_out;

    int n = in_sizes[0] / 2;  // coords is (N, 2)
    int nb = (n + 15) / 16;
    int blocks = 768;         // 3 blocks/CU (50.25 KB LDS), 4 waves each
    int maxb = (nb + 3) / 4;
    if (blocks > maxb) blocks = maxb;
    hipLaunchKernelGGL(siren_mfma_kernel, dim3(blocks), dim3(256), 0, stream,
                       coords, W0, b0, W1, b1, W2, b2, W3, b3, W4, b4, out, n);
}